// Round 10
// baseline (1295.837 us; speedup 1.0000x reference)
//
#include <hip/hip_runtime.h>

#define CDIM   512
#define NTOK   4096
#define TOT    (CDIM*NTOK)
#define MLPD   4096
#define EPS    1e-5f
#define QSCALE 0.1803368801111204f   // 0.125 * log2(e): softmax scale + exp2 conversion, folded into wq

typedef _Float16 f16;
typedef _Float16 f16x4 __attribute__((ext_vector_type(4)));
typedef _Float16 f16x8 __attribute__((ext_vector_type(8)));
typedef float    f32x4 __attribute__((ext_vector_type(4)));

typedef __attribute__((address_space(3))) void lds_void;
typedef const __attribute__((address_space(1))) void glb_void;

__device__ __forceinline__ void gload16(const void* g, void* l) {
  __builtin_amdgcn_global_load_lds((glb_void*)g, (lds_void*)l, 16, 0, 0);
}

__device__ __forceinline__ f32x4 zero4() { f32x4 z; z[0]=0.f; z[1]=0.f; z[2]=0.f; z[3]=0.f; return z; }

// =====================================================================
// weight staging kernels (fp32 -> f16, permutations baked in)
// =====================================================================
__global__ __launch_bounds__(256) void cvt_qkv(const float* __restrict__ wq,
                                               const float* __restrict__ wk,
                                               const float* __restrict__ wv,
                                               f16* __restrict__ dst) {
  int i = blockIdx.x * 256 + threadIdx.x;       // 8-elem unit, total 393216
  int k0 = (i & 63) * 8;
  int rowglob = i >> 6;
  int l = rowglob / 1536;
  int n = rowglob - l * 1536;
  int sect = n >> 9, nn = n & 511;
  int h = nn >> 6, hd = nn & 63;
  int c = hd * 8 + h;
  const float* base = (sect == 0) ? wq : (sect == 1) ? wk : wv;
  const float* src = base + (size_t)l * 262144 + c * 512 + k0;
  float scl = (sect == 0) ? QSCALE : 1.f;
  float4 a = *(const float4*)src;
  float4 b = *(const float4*)(src + 4);
  f16x8 o;
  o[0]=(f16)(a.x*scl); o[1]=(f16)(a.y*scl); o[2]=(f16)(a.z*scl); o[3]=(f16)(a.w*scl);
  o[4]=(f16)(b.x*scl); o[5]=(f16)(b.y*scl); o[6]=(f16)(b.z*scl); o[7]=(f16)(b.w*scl);
  *(f16x8*)&dst[(size_t)l * 786432 + (size_t)n * 512 + k0] = o;
}

__global__ __launch_bounds__(256) void cvt_wp(const float* __restrict__ wp,
                                              f16* __restrict__ dst) {
  int i = blockIdx.x * 256 + threadIdx.x;       // 8-elem unit, total 131072
  int d0 = (i & 63) * 8;
  int rowglob = i >> 6;
  int l = rowglob >> 9, n = rowglob & 511;
  int h = d0 >> 6;
  const float* src = wp + (size_t)l * 262144 + (size_t)n * 512;
  f16x8 o;
#pragma unroll
  for (int u = 0; u < 8; ++u) {
    int hd = (d0 + u) & 63;
    o[u] = (f16)src[hd * 8 + h];
  }
  *(f16x8*)&dst[(size_t)l * 262144 + (size_t)n * 512 + d0] = o;
}

__global__ __launch_bounds__(256) void cvt_12(const float* __restrict__ w1,
                                              const float* __restrict__ w2,
                                              f16* __restrict__ d1,
                                              f16* __restrict__ d2) {
  int i = blockIdx.x * 256 + threadIdx.x;       // 8-elem unit
  const float* src = blockIdx.y ? w2 : w1;
  f16* dst = blockIdx.y ? d2 : d1;
  size_t e = (size_t)i * 8;
  float4 a = *(const float4*)(src + e);
  float4 b = *(const float4*)(src + e + 4);
  f16x8 o;
  o[0]=(f16)a.x; o[1]=(f16)a.y; o[2]=(f16)a.z; o[3]=(f16)a.w;
  o[4]=(f16)b.x; o[5]=(f16)b.y; o[6]=(f16)b.z; o[7]=(f16)b.w;
  *(f16x8*)&dst[e] = o;
}

// =====================================================================
// fp32 tiled transpose (+ optional GN stats accumulation)
// =====================================================================
template <bool STATS>
__global__ __launch_bounds__(256) void transpose_k(const float* __restrict__ src,
                                                   float* __restrict__ dst,
                                                   int R, int C,
                                                   float* __restrict__ stats) {
  __shared__ float t[64][65];
  int c0 = blockIdx.x * 64, r0 = blockIdx.y * 64;
  float s = 0.f, q = 0.f;
  for (int id = threadIdx.x; id < 1024; id += 256) {
    int row = id >> 4, cc = id & 15;
    float4 v = *(const float4*)&src[(size_t)(r0 + row) * C + c0 + cc * 4];
    *(float4*)&t[row][cc * 4] = v;
    if (STATS) {
      s += (v.x + v.y) + (v.z + v.w);
      q += (v.x*v.x + v.y*v.y) + (v.z*v.z + v.w*v.w);
    }
  }
  __syncthreads();
  for (int id = threadIdx.x; id < 1024; id += 256) {
    int row = id >> 4, cc = id & 15;
    float4 o;
    o.x = t[cc*4+0][row]; o.y = t[cc*4+1][row];
    o.z = t[cc*4+2][row]; o.w = t[cc*4+3][row];
    *(float4*)&dst[(size_t)(c0 + row) * R + r0 + cc * 4] = o;
  }
  if (STATS) {
#pragma unroll
    for (int off = 32; off > 0; off >>= 1) {
      s += __shfl_down(s, off);
      q += __shfl_down(q, off);
    }
    if ((threadIdx.x & 63) == 0) {
      atomicAdd(&stats[0], s);
      atomicAdd(&stats[1], q);
    }
  }
}

// =====================================================================
// MFMA f16 GEMM. B via gload_lds (pre-swizzled source).
// A: FUSE=false -> f16 gload_lds; FUSE=true -> reg-staged from fp32 xcur
// with GroupNorm applied inline (mu/rs from raw stats, per-channel g,b).
// MODE 0: f16 store (LDS-bounced); 1: +bias+relu f16 store;
// MODE 2: direct fp32 RMW C += acc+bias, GN stats fused in registers.
// =====================================================================
template <int BM, int BN, int MODE, bool FUSE>
__global__ __launch_bounds__(256) void hgemm2(const f16* __restrict__ A,
                                              const float* __restrict__ Af32,
                                              const f16* __restrict__ Bw,
                                              const float* __restrict__ gnst,
                                              const float* __restrict__ g,
                                              const float* __restrict__ b,
                                              const float* __restrict__ bias,
                                              f16* __restrict__ Cf16,
                                              float* __restrict__ Cf32,
                                              float* __restrict__ stats,
                                              int N, int K) {
  constexpr int MB = BM / 32, NB = BN / 32;     // fragments per wave (2x2 wave grid)
  __shared__ __align__(16) f16 SM[(BM + BN) * 64];
  f16* As = SM;
  f16* Bs = SM + BM * 64;

  const int tid = threadIdx.x;
  const int lane = tid & 63, wid = tid >> 6;
  const int wm = wid >> 1, wn = wid & 1;
  const int m0 = blockIdx.y * BM, n0 = blockIdx.x * BN;
  const int l15 = lane & 15, hi = lane >> 4;

  float mu = 0.f, rs = 0.f;
  if constexpr (FUSE) {
    mu = gnst[0] * (1.f / TOT);
    float var = gnst[1] * (1.f / TOT) - mu * mu;
    rs = rsqrtf(var + EPS);
  }

  f32x4 acc[MB][NB];
#pragma unroll
  for (int mb = 0; mb < MB; ++mb)
#pragma unroll
    for (int nb = 0; nb < NB; ++nb) acc[mb][nb] = zero4();

  for (int k0 = 0; k0 < K; k0 += 64) {
    if constexpr (FUSE) {
      int ch = k0 + (tid & 7) * 8;              // per-thread channel base (loop-invariant in j)
      float4 G0 = *(const float4*)&g[ch], G1 = *(const float4*)&g[ch + 4];
      float4 B0 = *(const float4*)&b[ch], B1 = *(const float4*)&b[ch + 4];
      float gg[8] = {G0.x*rs, G0.y*rs, G0.z*rs, G0.w*rs, G1.x*rs, G1.y*rs, G1.z*rs, G1.w*rs};
      float bb[8] = {B0.x - mu*gg[0], B0.y - mu*gg[1], B0.z - mu*gg[2], B0.w - mu*gg[3],
                     B1.x - mu*gg[4], B1.y - mu*gg[5], B1.z - mu*gg[6], B1.w - mu*gg[7]};
#pragma unroll
      for (int j = 0; j < BM / 32; ++j) {
        int flat = j * 256 + tid;
        int row = flat >> 3, c8 = flat & 7;
        const float* srcp = &Af32[(size_t)(m0 + row) * K + ch];
        float4 a0 = *(const float4*)srcp;
        float4 a1 = *(const float4*)(srcp + 4);
        f16x8 ov;
        ov[0]=(f16)(a0.x*gg[0]+bb[0]); ov[1]=(f16)(a0.y*gg[1]+bb[1]);
        ov[2]=(f16)(a0.z*gg[2]+bb[2]); ov[3]=(f16)(a0.w*gg[3]+bb[3]);
        ov[4]=(f16)(a1.x*gg[4]+bb[4]); ov[5]=(f16)(a1.y*gg[5]+bb[5]);
        ov[6]=(f16)(a1.z*gg[6]+bb[6]); ov[7]=(f16)(a1.w*gg[7]+bb[7]);
        *(f16x8*)&As[row * 64 + ((c8 ^ (row & 7)) * 8)] = ov;
      }
    } else {
#pragma unroll
      for (int j = 0; j < BM / 32; ++j) {
        int flat = j * 256 + tid;
        int row = flat >> 3, c = flat & 7;
        gload16(&A[(size_t)(m0 + row) * K + k0 + ((c ^ (row & 7)) * 8)],
                &As[(j * 256 + wid * 64) * 8]);
      }
    }
#pragma unroll
    for (int j = 0; j < BN / 32; ++j) {
      int flat = j * 256 + tid;
      int row = flat >> 3, c = flat & 7;
      gload16(&Bw[(size_t)(n0 + row) * K + k0 + ((c ^ (row & 7)) * 8)],
              &Bs[(j * 256 + wid * 64) * 8]);
    }
    asm volatile("s_waitcnt vmcnt(0)" ::: "memory");
    __syncthreads();
#pragma unroll
    for (int ks = 0; ks < 2; ++ks) {
      f16x8 af[MB], bf[NB];
#pragma unroll
      for (int mb = 0; mb < MB; ++mb) {
        int row = wm * (BM / 2) + mb * 16 + l15;
        af[mb] = *(const f16x8*)&As[row * 64 + ((ks * 32 + hi * 8) ^ ((row & 7) * 8))];
      }
#pragma unroll
      for (int nb = 0; nb < NB; ++nb) {
        int row = wn * (BN / 2) + nb * 16 + l15;
        bf[nb] = *(const f16x8*)&Bs[row * 64 + ((ks * 32 + hi * 8) ^ ((row & 7) * 8))];
      }
#pragma unroll
      for (int mb = 0; mb < MB; ++mb)
#pragma unroll
        for (int nb = 0; nb < NB; ++nb)
          acc[mb][nb] = __builtin_amdgcn_mfma_f32_16x16x32_f16(af[mb], bf[nb], acc[mb][nb], 0, 0, 0);
    }
    __syncthreads();
  }

  if constexpr (MODE <= 1) {
    f16* Co = SM;                               // BM*BN f16 == (BM+BN)*64 exactly
#pragma unroll
    for (int mb = 0; mb < MB; ++mb)
#pragma unroll
      for (int nb = 0; nb < NB; ++nb) {
        int colb = wn * (BN / 2) + nb * 16 + l15;
        float bv = 0.f;
        if constexpr (MODE == 1) bv = bias[n0 + colb];
#pragma unroll
        for (int r = 0; r < 4; ++r) {
          int row = wm * (BM / 2) + mb * 16 + hi * 4 + r;
          float v = acc[mb][nb][r];
          if constexpr (MODE == 1) v = fmaxf(v + bv, 0.f);
          Co[row * BN + (colb ^ ((row & 7) * 8))] = (f16)v;
        }
      }
    __syncthreads();
#pragma unroll
    for (int j = 0; j < BM * BN / 2048; ++j) {
      int flat = j * 256 + tid;
      int row = flat / (BN / 8), c = flat % (BN / 8);
      f16x8 v = *(const f16x8*)&Co[row * BN + ((c * 8) ^ ((row & 7) * 8))];
      *(f16x8*)&Cf16[(size_t)(m0 + row) * N + n0 + c * 8] = v;
    }
  } else {
    // MODE 2: direct fp32 RMW (+bias); GN stats accumulated in registers
    float s_acc = 0.f, q_acc = 0.f;
    const int rbase = m0 + wm * (BM / 2) + hi * 4;
#pragma unroll
    for (int mb = 0; mb < MB; ++mb) {
#pragma unroll
      for (int nb = 0; nb < NB; ++nb) {
        int col = n0 + wn * (BN / 2) + nb * 16 + l15;
        float bv = bias[col];
#pragma unroll
        for (int r = 0; r < 4; ++r) {
          int row = rbase + mb * 16 + r;
          float* gp = &Cf32[(size_t)row * N + col];
          float rr = *gp + acc[mb][nb][r] + bv;
          *gp = rr;
          s_acc += rr;
          q_acc += rr * rr;
        }
      }
    }
#pragma unroll
    for (int off = 32; off > 0; off >>= 1) {
      s_acc += __shfl_down(s_acc, off);
      q_acc += __shfl_down(q_acc, off);
    }
    if (lane == 0) {
      atomicAdd(&stats[0], s_acc);
      atomicAdd(&stats[1], q_acc);
    }
  }
}

// =====================================================================
// V transpose: vc2[hm][tok] = qkv[tok][1024+hm]  (hm = h*64+hd head-major)
// =====================================================================
__global__ __launch_bounds__(256) void perm_v2(const f16* __restrict__ qkv,
                                               f16* __restrict__ vc) {
  __shared__ f16 t[64][72];
  int t0 = blockIdx.x * 64, c0 = blockIdx.y * 64;
  for (int id = threadIdx.x; id < 512; id += 256) {
    int row = id >> 3, cc = id & 7;
    *(f16x8*)&t[row][cc * 8] =
        *(const f16x8*)&qkv[(size_t)(t0 + row) * 1536 + 1024 + c0 + cc * 8];
  }
  __syncthreads();
  for (int id = threadIdx.x; id < 512; id += 256) {
    int row = id >> 3, cc = id & 7;
    f16x8 o;
#pragma unroll
    for (int u = 0; u < 8; ++u) o[u] = t[cc * 8 + u][row];
    *(f16x8*)&vc[(size_t)(c0 + row) * NTOK + t0 + cc * 8] = o;
  }
}

// =====================================================================
// MFMA f16 flash attention, split-KV x2, head->XCD affinity.
// 1D grid 1024: id&7 = head (XCD = id%8), (id>>3)&1 = split, id>>4 = q-tile.
// Each split handles 32 of 64 kv-blocks, stores UNNORMALIZED O (f16)
// + l (f32); attn_combine merges (linear, fixed-max exp2 softmax).
// =====================================================================
__global__ __launch_bounds__(256) void attn2(const f16* __restrict__ qkv,
                                             const f16* __restrict__ vc,
                                             f16* __restrict__ Op,
                                             float* __restrict__ lp) {
  __shared__ __align__(16) f16 Ks[2][64 * 64];   // 16 KB
  __shared__ __align__(16) f16 Vs[2][64 * 64];   // 16 KB
  __shared__ __align__(16) f16 Ps[64 * 64];      // 8 KB

  const int tid = threadIdx.x;
  const int lane = tid & 63, w = tid >> 6;
  const int l15 = lane & 15, hi = lane >> 4;
  const int id = blockIdx.x;
  const int h = id & 7, split = (id >> 3) & 1, q0 = (id >> 4) * 64;
  const int kbase = split * 32;

  const f16* qrow = qkv + (size_t)(q0 + w * 16 + l15) * 1536 + h * 64;
  f16x8 qf0 = *(const f16x8*)(qrow + hi * 8);
  f16x8 qf1 = *(const f16x8*)(qrow + 32 + hi * 8);

  float l_run[4] = {0.f, 0.f, 0.f, 0.f};
  f32x4 oacc[4];
#pragma unroll
  for (int nbh = 0; nbh < 4; ++nbh) oacc[nbh] = zero4();

  auto stageK = [&](int buf, int kb) {
#pragma unroll
    for (int j = 0; j < 2; ++j) {
      int flat = j * 256 + tid;
      int rho = flat >> 3, c = flat & 7;
      int key = kb * 64 + ((rho & 15) * 4 + (rho >> 4));   // sigma
      gload16(qkv + (size_t)key * 1536 + 512 + h * 64 + ((c ^ (rho & 7)) * 8),
              &Ks[buf][(j * 256 + w * 64) * 8]);
    }
  };
  auto stageV = [&](int buf, int kb) {
#pragma unroll
    for (int j = 0; j < 2; ++j) {
      int flat = j * 256 + tid;
      int hd = flat >> 3, c = flat & 7;
      gload16(vc + (size_t)(h * 64 + hd) * NTOK + kb * 64 + ((c ^ (hd & 7)) * 8),
              &Vs[buf][(j * 256 + w * 64) * 8]);
    }
  };

  stageK(0, kbase); stageV(0, kbase);
  asm volatile("s_waitcnt vmcnt(0)" ::: "memory");
  __syncthreads();

  for (int kb2 = 0; kb2 < 32; ++kb2) {
    int cur = kb2 & 1;
    if (kb2 < 31) { stageK(cur ^ 1, kbase + kb2 + 1); stageV(cur ^ 1, kbase + kb2 + 1); }

    // QK^T (S in log2 units; Q pre-scaled via weights)
    const f16* Kb = &Ks[cur][0];
    f32x4 sacc[4];
#pragma unroll
    for (int nb = 0; nb < 4; ++nb) sacc[nb] = zero4();
    __builtin_amdgcn_s_setprio(1);
#pragma unroll
    for (int nb = 0; nb < 4; ++nb) {
      int row = nb * 16 + l15;
      int sw = (row & 7) * 8;
      f16x8 k0f = *(const f16x8*)&Kb[row * 64 + ((hi * 8) ^ sw)];
      f16x8 k1f = *(const f16x8*)&Kb[row * 64 + ((32 + hi * 8) ^ sw)];
      sacc[nb] = __builtin_amdgcn_mfma_f32_16x16x32_f16(qf0, k0f, sacc[nb], 0, 0, 0);
      sacc[nb] = __builtin_amdgcn_mfma_f32_16x16x32_f16(qf1, k1f, sacc[nb], 0, 0, 0);
    }
    __builtin_amdgcn_s_setprio(0);

    // fixed-max softmax: P = exp2(S); contiguous b64 P write (swizzled)
#pragma unroll
    for (int r = 0; r < 4; ++r) {
      int prow = w * 16 + hi * 4 + r;
      f16x4 pv;
      float ps = 0.f;
#pragma unroll
      for (int nb = 0; nb < 4; ++nb) {
        float p = exp2f(sacc[nb][r]);
        ps += p;
        pv[nb] = (f16)p;                         // key = l15*4 + nb (contiguous)
      }
      *(f16x4*)&Ps[prow * 64 + ((l15 * 4) ^ ((prow & 7) * 8))] = pv;
#pragma unroll
      for (int off = 1; off < 16; off <<= 1) ps += __shfl_xor(ps, off);
      l_run[r] += ps;
    }

    // O += P * V
    const f16* Vb = &Vs[cur][0];
    {
      int prow = w * 16 + l15;
      int psw = (prow & 7) * 8;
      __builtin_amdgcn_s_setprio(1);
#pragma unroll
      for (int ks2 = 0; ks2 < 2; ++ks2) {
        f16x8 pf = *(const f16x8*)&Ps[prow * 64 + ((ks2 * 32 + hi * 8) ^ psw)];
#pragma unroll
        for (int nbh = 0; nbh < 4; ++nbh) {
          int vrow = nbh * 16 + l15;
          f16x8 vf = *(const f16x8*)&Vb[vrow * 64 + ((ks2 * 32 + hi * 8) ^ ((vrow & 7) * 8))];
          oacc[nbh] = __builtin_amdgcn_mfma_f32_16x16x32_f16(pf, vf, oacc[nbh], 0, 0, 0);
        }
      }
      __builtin_amdgcn_s_setprio(0);
    }
    asm volatile("s_waitcnt vmcnt(0)" ::: "memory");
    __syncthreads();
  }

  // store l (per q-row), bounce unnormalized O through Ps, vector store
  if (l15 == 0) {
#pragma unroll
    for (int r = 0; r < 4; ++r)
      lp[(size_t)(split * 8 + h) * NTOK + q0 + w * 16 + hi * 4 + r] = l_run[r];
  }
  f16* Ot = Ps;
#pragma unroll
  for (int r = 0; r < 4; ++r) {
    int row = w * 16 + hi * 4 + r;
    int sw = (row & 7) * 8;
#pragma unroll
    for (int nbh = 0; nbh < 4; ++nbh) {
      int col = nbh * 16 + l15;
      Ot[row * 64 + (col ^ sw)] = (f16)oacc[nbh][r];
    }
  }
  __syncthreads();
#pragma unroll
  for (int j = 0; j < 2; ++j) {
    int flat = j * 256 + tid;
    int row = flat >> 3, c = flat & 7;
    f16x8 v = *(const f16x8*)&Ot[row * 64 + ((c ^ (row & 7)) * 8)];
    *(f16x8*)&Op[(size_t)split * TOT + (size_t)(q0 + row) * 512 + h * 64 + c * 8] = v;
  }
}

// combine: oatt = (Op[0] + Op[1]) / (l0 + l1)
__global__ __launch_bounds__(256) void attn_combine(const f16* __restrict__ Op,
                                                    const float* __restrict__ lp,
                                                    f16* __restrict__ oatt) {
  int i = blockIdx.x * 256 + threadIdx.x;       // 8-elem unit, total 262144
  int tok = i >> 6;
  int c0 = (i & 63) * 8;
  int h = c0 >> 6;
  f16x8 a = *(const f16x8*)&Op[(size_t)tok * 512 + c0];
  f16x8 b = *(const f16x8*)&Op[(size_t)TOT + (size_t)tok * 512 + c0];
  float l = lp[(size_t)h * NTOK + tok] + lp[(size_t)(8 + h) * NTOK + tok];
  float inv = 1.f / l;
  f16x8 o;
#pragma unroll
  for (int u = 0; u < 8; ++u) o[u] = (f16)(((float)a[u] + (float)b[u]) * inv);
  *(f16x8*)&oatt[(size_t)tok * 512 + c0] = o;
}

// =====================================================================
// host-side orchestration
// =====================================================================
extern "C" void kernel_launch(void* const* d_in, const int* in_sizes, int n_in,
                              void* d_out, int out_size, void* d_ws, size_t ws_size,
                              hipStream_t stream) {
  const float* x   = (const float*)d_in[0];
  const float* g1  = (const float*)d_in[1];
  const float* b1  = (const float*)d_in[2];
  const float* g2  = (const float*)d_in[3];
  const float* b2  = (const float*)d_in[4];
  const float* wq  = (const float*)d_in[5];
  const float* wk  = (const float*)d_in[6];
  const float* wv  = (const float*)d_in[7];
  const float* wp  = (const float*)d_in[8];
  const float* bp  = (const float*)d_in[9];
  const float* w1  = (const float*)d_in[10];
  const float* bb1 = (const float*)d_in[11];
  const float* w2  = (const float*)d_in[12];
  const float* bb2 = (const float*)d_in[13];

  char* base = (char*)d_ws;
  size_t off = 0;
  f16* wqkvF = (f16*)(base + off); off += (size_t)4 * 786432 * 2;
  f16* wpF   = (f16*)(base + off); off += (size_t)4 * 262144 * 2;
  f16* w1F   = (f16*)(base + off); off += (size_t)4 * 2097152 * 2;
  f16* w2F   = (f16*)(base + off); off += (size_t)4 * 2097152 * 2;
  float* xcur = (float*)(base + off); off += (size_t)TOT * 4;
  float* stats_raw = (float*)(base + off); off += 256;
  float* lp = (float*)(base + off); off += (size_t)2 * 8 * NTOK * 4;   // 256 KB
  char* U = base + off; off += 33554432;
  f16* qkvT = (f16*)U;                      // [4096][1536]  12 MB
  f16* vc2  = (f16*)(U + 12582912);         // [512][4096]    4 MB
  f16* Op   = (f16*)(U + 16777216);         // [2][4096][512] 8 MB (unnormalized)
  f16* oatt = (f16*)(U + 25165824);         // [4096][512]    4 MB
  f16* hT   = (f16*)U;                      // [4096][4096] (FFN phase, overlaps all)

  if (ws_size < off) return;

  hipMemsetAsync(stats_raw, 0, 18 * sizeof(float), stream);

  cvt_qkv<<<1536, 256, 0, stream>>>(wq, wk, wv, wqkvF);
  cvt_wp<<<512, 256, 0, stream>>>(wp, wpF);
  cvt_12<<<dim3(4096, 2), 256, 0, stream>>>(w1, w2, w1F, w2F);

  transpose_k<true><<<dim3(64, 8), 256, 0, stream>>>(x, xcur, 512, 4096, stats_raw);

  for (int l = 0; l < 4; ++l) {
    // --- x = x + attn(GN1(x)) ---  (GN fused into qkv-GEMM A-staging)
    hgemm2<128, 128, 0, true><<<dim3(12, 32), 256, 0, stream>>>(
        nullptr, xcur, wqkvF + (size_t)l * 786432, stats_raw + 2 * (2 * l),
        g1 + l * CDIM, b1 + l * CDIM, nullptr, qkvT, nullptr, nullptr, 1536, 512);
    perm_v2<<<dim3(64, 8), 256, 0, stream>>>(qkvT, vc2);
    attn2<<<1024, 256, 0, stream>>>(qkvT, vc2, Op, lp);
    attn_combine<<<1024, 256, 0, stream>>>(Op, lp, oatt);
    hgemm2<64, 128, 2, false><<<dim3(4, 64), 256, 0, stream>>>(
        oatt, nullptr, wpF + (size_t)l * 262144, nullptr, nullptr, nullptr,
        bp + l * CDIM, nullptr, xcur, stats_raw + 2 * (2 * l + 1), 512, 512);

    // --- x = x + FFN(GN2(x)) ---  (GN fused into w1-GEMM A-staging)
    hgemm2<128, 128, 1, true><<<dim3(32, 32), 256, 0, stream>>>(
        nullptr, xcur, w1F + (size_t)l * 2097152, stats_raw + 2 * (2 * l + 1),
        g2 + l * CDIM, b2 + l * CDIM, bb1 + l * MLPD, hT, nullptr, nullptr, 4096, 512);
    hgemm2<64, 128, 2, false><<<dim3(4, 64), 256, 0, stream>>>(
        hT, nullptr, w2F + (size_t)l * 2097152, nullptr, nullptr, nullptr,
        bb2 + l * CDIM, nullptr, xcur, stats_raw + 2 * (2 * l + 2), 512, 4096);
  }

  transpose_k<false><<<dim3(8, 64), 256, 0, stream>>>(xcur, (float*)d_out, 4096, 512, nullptr);
}